// Round 1
// baseline (254.722 us; speedup 1.0000x reference)
//
#include <hip/hip_runtime.h>

// Problem constants (from reference): b=1, m=128, n=256, c=22
#define NC 22
#define NCC (NC*NC)        // 484 floats per (i,j) tile
#define NJ 256
#define NI 256
#define NM 128
#define JG 8               // j's per staging group
#define TILE (JG*NCC)      // 3872 floats = 15488 B
#define NG (NJ/JG)         // 32 groups

// hi[m,i,c] = sum_j eij[i,j,c,v[m,j]] * mask_vec[v[m,j]]
// motifs[m,i,c] = ei[i,c] + hi[m,i,c]
// logits[m,i]   = motifs[m,i,v[m,i]]
__global__ __launch_bounds__(256) void potts_main(
    const int*   __restrict__ variant,   // [128,256] int32
    const float* __restrict__ eij,       // [256,256,22,22]
    const float* __restrict__ ei,        // [256,22]
    const float* __restrict__ mask_vec,  // [22]
    float*       __restrict__ out_motifs,// [128,256,22]
    float*       __restrict__ out_logits)// [128,256]
{
    const int i    = blockIdx.x;
    const int tid  = threadIdx.x;
    const int m    = tid & 127;
    const int half = tid >> 7;
    const int cc0  = half * 11;

    __shared__ float lds[2][TILE];

    // Staging map: round r stages float4 index f = r*256+tid (4 rounds cover 968 float4)
    // Pre-resolve per-component d = e%22 and its mask weight (folded at LDS write).
    float mreg[4][4];
    int   fidx[4];
    bool  fact[4];
    #pragma unroll
    for (int r = 0; r < 4; ++r) {
        int f = r * 256 + tid;
        fidx[r] = f;
        fact[r] = (4 * f < TILE);
        #pragma unroll
        for (int t = 0; t < 4; ++t) {
            int e = 4 * f + t;
            mreg[r][t] = fact[r] ? mask_vec[e % NC] : 0.f;
        }
    }

    const float* gbase = eij + (size_t)i * (NJ * NCC);

    float acc[11];
    #pragma unroll
    for (int k = 0; k < 11; ++k) acc[k] = 0.f;

    // Prefetch group 0 into registers
    float4 pf[4];
    #pragma unroll
    for (int r = 0; r < 4; ++r)
        if (fact[r]) pf[r] = ((const float4*)gbase)[fidx[r]];

    for (int g = 0; g < NG; ++g) {
        float* buf = lds[g & 1];

        // LDS write (mask folded), conflict-free lane-linear b128
        #pragma unroll
        for (int r = 0; r < 4; ++r) {
            if (fact[r]) {
                float4 v = pf[r];
                v.x *= mreg[r][0]; v.y *= mreg[r][1];
                v.z *= mreg[r][2]; v.w *= mreg[r][3];
                ((float4*)buf)[fidx[r]] = v;
            }
        }
        __syncthreads();
        // One barrier per group is sufficient with double buffering:
        // next write to lds[(g+1)&1] happens only after all waves passed this
        // barrier, i.e. after all reads of that buffer (from group g-1) retired.

        // Prefetch next group while we compute
        if (g + 1 < NG) {
            const float4* gnext = (const float4*)(gbase + (size_t)(g + 1) * TILE);
            #pragma unroll
            for (int r = 0; r < 4; ++r)
                if (fact[r]) pf[r] = gnext[fidx[r]];
        }

        // Variant indices for this group's 8 j's (both halves of an m load the
        // same int4 — L1 broadcast)
        const int j0 = g * JG;
        const int4 va = *(const int4*)(variant + m * NJ + j0);
        const int4 vb = *(const int4*)(variant + m * NJ + j0 + 4);
        const int vs[JG] = {va.x, va.y, va.z, va.w, vb.x, vb.y, vb.z, vb.w};

        // Gather-accumulate: addr = const + v within a wave -> 22 distinct
        // banks, no conflicts; equal-v lanes broadcast.
        #pragma unroll
        for (int jj = 0; jj < JG; ++jj) {
            const float* p = buf + jj * NCC + cc0 * NC + vs[jj];
            #pragma unroll
            for (int k = 0; k < 11; ++k)
                acc[k] += p[k * NC];
        }
    }

    // Epilogue: motifs = ei + hi; logits = one-hot pick at v[m,i]
    const float* eirow = ei + i * NC;
    float* mout = out_motifs + ((size_t)m * NI + i) * NC;
    const int vi = variant[m * NJ + i];
    float logit = 0.f;
    #pragma unroll
    for (int k = 0; k < 11; ++k) {
        const float mo = acc[k] + eirow[cc0 + k];
        mout[cc0 + k] = mo;
        if (cc0 + k == vi) logit = mo;
    }
    if (vi >= cc0 && vi < cc0 + 11)
        out_logits[m * NI + i] = logit;
}

// variant_logit[m] = sigma * sum_i (logits[m,i]-logits[0,i]) * vm[m,i]*vm[0,i]
__global__ __launch_bounds__(64) void potts_pool(
    const float* __restrict__ logits,  // [128,256] (already in d_out)
    const float* __restrict__ vmask,   // [128,256]
    const float* __restrict__ sigma,   // [1]
    float*       __restrict__ out_vl)  // [128]
{
    const int m    = blockIdx.x;
    const int lane = threadIdx.x;
    float s = 0.f;
    #pragma unroll
    for (int q = 0; q < 4; ++q) {
        const int i = lane + 64 * q;
        const float vl = logits[m * NI + i] - logits[i];
        s += vl * vmask[m * NI + i] * vmask[i];
    }
    #pragma unroll
    for (int off = 32; off > 0; off >>= 1)
        s += __shfl_down(s, off, 64);
    if (lane == 0) out_vl[m] = sigma[0] * s;
}

extern "C" void kernel_launch(void* const* d_in, const int* in_sizes, int n_in,
                              void* d_out, int out_size, void* d_ws, size_t ws_size,
                              hipStream_t stream) {
    const int*   variant  = (const int*)  d_in[0];  // [1,128,256] int32
    const float* vmask    = (const float*)d_in[1];  // [1,128,256]
    const float* eij      = (const float*)d_in[2];  // [1,256,256,22,22]
    const float* ei       = (const float*)d_in[3];  // [1,256,22]
    const float* mask_vec = (const float*)d_in[4];  // [22]
    const float* sigma    = (const float*)d_in[5];  // [1]

    float* out        = (float*)d_out;
    float* out_motifs = out;                        // 128*256*22 = 720896
    float* out_logits = out_motifs + NM * NI * NC;  // 128*256    =  32768
    float* out_vl     = out_logits + NM * NI;       // 128

    potts_main<<<NI, 256, 0, stream>>>(variant, eij, ei, mask_vec,
                                       out_motifs, out_logits);
    potts_pool<<<NM, 64, 0, stream>>>(out_logits, vmask, sigma, out_vl);
}